// Round 13
// baseline (264.034 us; speedup 1.0000x reference)
//
#include <hip/hip_runtime.h>
#include <hip/hip_cooperative_groups.h>

namespace cg = cooperative_groups;

#define NV  778
#define NK  146    // coef: 1 (template) + 10 (beta) + 135 (pose_feature)
#define NKQ 152    // Gq rows padded (rows 146..151 zero)
#define GC  8      // batches per block
#define VCH 49     // v-chunk per Gq fold unit (16 chunks cover 778)
#define NU  2533   // stage-1 units: 2336 Gq + 132 SJ/JT + 64 WJ + 1 fingers

#define FV0 734
#define FV1 333
#define FV2 443
#define FV3 555
#define FV4 678

__device__ __forceinline__ const float* d_row(int k,
                                              const float* vt,
                                              const float* sd,
                                              const float* pd) {
    return (k == 0) ? vt : (k <= 10 ? sd + (size_t)(k-1)*(NV*3)
                                    : pd + (size_t)(k-11)*(NV*3));
}

// ---------------------------------------------------------------------------
// k_all: single cooperative kernel.
//   stage 0: zero Gq (grid-stride) + pose PCA + Rodrigues -> coefG/R0G
//   grid.sync
//   stage 1: folds (Gq chunks w/ LDS staging + atomics; SJ/JT; WJ; Dfing)
//   grid.sync
//   stage 2: per-batch GEMM + kinematic chain + joints + fingers (R12 kC)
// ---------------------------------------------------------------------------
__launch_bounds__(256)
__global__ void k_all(const float* __restrict__ vt,
                      const float* __restrict__ sd,
                      const float* __restrict__ pd,
                      const float* __restrict__ jreg,
                      const float* __restrict__ wts,
                      const float* __restrict__ beta,
                      const float* __restrict__ theta,
                      const float* __restrict__ hm,
                      const float* __restrict__ hc,
                      float* __restrict__ SJ, float* __restrict__ JT,
                      float* __restrict__ WJ, float* __restrict__ Gq,
                      float* __restrict__ coefG, float* __restrict__ R0G,
                      float* __restrict__ Dfing, float* __restrict__ Wfing,
                      float* __restrict__ out,
                      int Btot)
{
    cg::grid_group grid = cg::this_grid();
    const int tid  = threadIdx.x;
    const int blk  = blockIdx.x;
    const int nblk = gridDim.x;
    const int w = tid >> 6, t = tid & 63;

    // stage-0 LDS
    __shared__ float p_hc[2025];
    __shared__ float p_th[8][48];
    __shared__ float p_pose[8][45];
    // stage-1 LDS
    __shared__ float l_j[VCH*16];
    __shared__ float l_w[VCH*16];
    __shared__ float l_d[VCH*3];
    // stage-2 LDS
    __shared__ float s_SJ[480];
    __shared__ float s_JT[48];
    __shared__ float s_WJ[256];
    __shared__ __align__(16) float s_coef[GC][152];
    __shared__ float s_R0[GC][9];
    __shared__ float s_A[GC][192];
    __shared__ float s_J[GC][48];
    __shared__ float s_vpf[GC][16];
    __shared__ float s_fred[GC][15][2];

    // ================= stage 0: zero Gq + pose/PCA/Rodrigues =================
    for (int i = blk*256 + tid; i < NKQ*768; i += nblk*256) Gq[i] = 0.f;

    {
        const int b0 = blk * 8;
        for (int i = tid; i < 2025; i += 256) p_hc[i] = hc[i];
        for (int i = tid; i < 8*48; i += 256) {
            int g = i / 48, tt = i % 48, b = b0 + g;
            p_th[g][tt] = (b < Btot) ? theta[(size_t)b*48 + tt] : 0.f;
        }
        __syncthreads();
        for (int i = tid; i < 8*45; i += 256) {
            int g = i / 45, tt = i % 45;
            float acc = hm[tt];
            #pragma unroll 9
            for (int k = 0; k < 45; ++k) acc += p_th[g][3+k] * p_hc[k*45 + tt];
            p_pose[g][tt] = acc;
        }
        __syncthreads();
        if (tid < 128) {
            int g = tid >> 4, jt = tid & 15;
            int b = b0 + g;
            if (b < Btot) {
                float rx, ry, rz;
                if (jt == 0) { rx = p_th[g][0]; ry = p_th[g][1]; rz = p_th[g][2]; }
                else { rx = p_pose[g][3*(jt-1)+0]; ry = p_pose[g][3*(jt-1)+1]; rz = p_pose[g][3*(jt-1)+2]; }
                float ex = rx + 1e-8f, ey = ry + 1e-8f, ez = rz + 1e-8f;
                float angle = sqrtf(ex*ex + ey*ey + ez*ez);
                float inv = 1.f / angle;
                float x = rx*inv, y = ry*inv, z = rz*inv;
                float s  = sinf(angle);
                float c1 = 1.f - cosf(angle);
                float R[9];
                R[0] = 1.f + c1*(-(z*z + y*y));
                R[1] = -s*z + c1*(x*y);
                R[2] =  s*y + c1*(x*z);
                R[3] =  s*z + c1*(x*y);
                R[4] = 1.f + c1*(-(x*x + z*z));
                R[5] = -s*x + c1*(y*z);
                R[6] = -s*y + c1*(x*z);
                R[7] =  s*x + c1*(y*z);
                R[8] = 1.f + c1*(-(x*x + y*y));
                float* cg_ = coefG + (size_t)b*152;
                if (jt == 0) {
                    #pragma unroll
                    for (int i = 0; i < 9; ++i) R0G[(size_t)b*9 + i] = R[i];
                    cg_[0] = 1.f;
                    #pragma unroll
                    for (int k = 0; k < 10; ++k) cg_[1+k] = beta[(size_t)b*10 + k];
                    #pragma unroll
                    for (int k = 146; k < 152; ++k) cg_[k] = 0.f;
                } else {
                    #pragma unroll
                    for (int i = 0; i < 9; ++i)
                        cg_[11 + (jt-1)*9 + i] = R[i] - ((i % 4 == 0) ? 1.f : 0.f);
                }
            }
        }
    }
    grid.sync();

    // ================= stage 1: folds =================
    const int upb = (NU + nblk - 1) / nblk;
    for (int i = 0; i < upb; ++i) {
        const int u = blk*upb + i;
        if (u < 2336) {
            const int k = u >> 4, chunk = u & 15;
            const float* Drow = d_row(k, vt, sd, pd);
            const int v0 = chunk * VCH;
            const int v1 = (v0 + VCH < NV) ? (v0 + VCH) : NV;
            const int n = v1 - v0;
            __syncthreads();   // protect l_* reads of previous unit
            for (int e = tid; e < n*16; e += 256) l_j[e] = jreg[v0*16 + e];
            for (int e = tid; e < n*16; e += 256) l_w[e] = wts[v0*16 + e];
            for (int e = tid; e < n*3;  e += 256) l_d[e] = Drow[v0*3 + e];
            __syncthreads();
            const int J = tid >> 4, j = tid & 15;
            float a0 = 0.f, a1 = 0.f, a2 = 0.f;
            #pragma unroll 7
            for (int v = 0; v < n; ++v) {
                float pv = l_j[v*16 + J] * l_w[v*16 + j];
                a0 += l_d[v*3+0] * pv;
                a1 += l_d[v*3+1] * pv;
                a2 += l_d[v*3+2] * pv;
            }
            float* gp = Gq + ((size_t)k*256 + tid)*3;
            atomicAdd(gp+0, a0);
            atomicAdd(gp+1, a1);
            atomicAdd(gp+2, a2);
        } else if (u < 2468) {
            const int idx = (u - 2336)*4 + (tid >> 6);   // 0..527
            const int tt = tid & 63;
            const float* src; int jc;
            if (idx < 480) { int k = idx / 48; jc = idx % 48; src = sd + (size_t)k*(NV*3); }
            else           { jc = idx - 480;              src = vt; }
            int j = jc / 3, c = jc % 3;
            float acc = 0.f;
            for (int v = tt; v < NV; v += 64)
                acc += src[3*v + c] * jreg[v*16 + j];
            for (int off = 32; off; off >>= 1) acc += __shfl_down(acc, off, 64);
            if (tt == 0) { if (idx < 480) SJ[idx] = acc; else JT[jc] = acc; }
        } else if (u < 2532) {
            const int cidx = (u - 2468)*4 + (tid >> 6);  // 0..255
            const int tt = tid & 63;
            const int J = cidx >> 4, j = cidx & 15;
            float acc = 0.f;
            for (int v = tt; v < NV; v += 64)
                acc += jreg[v*16 + J] * wts[v*16 + j];
            for (int off = 32; off; off >>= 1) acc += __shfl_down(acc, off, 64);
            if (tt == 0) WJ[cidx] = acc;
        } else if (u == 2532) {
            const int fv[5] = {FV0, FV1, FV2, FV3, FV4};
            for (int e = tid; e < NK*15; e += 256) {
                int k = e / 15, r = e % 15, f = r / 3, q = r % 3;
                Dfing[e] = d_row(k, vt, sd, pd)[3*fv[f] + q];
            }
            if (tid < 80) {
                int f = tid >> 4, j = tid & 15;
                Wfing[tid] = wts[fv[f]*16 + j];
            }
        }
    }
    grid.sync();

    // ================= stage 2: per-batch (R12 kC body) =================
    const int b0 = blk * GC;

    // prefetch Gq group 0
    float cur0[8], cur1[8], cur2[8];
    #pragma unroll
    for (int kk = 0; kk < 8; ++kk) {
        const float* gq = Gq + ((size_t)kk*256 + tid)*3;
        cur0[kk] = gq[0]; cur1[kk] = gq[1]; cur2[kk] = gq[2];
    }

    for (int i = tid; i < 480; i += 256) s_SJ[i] = SJ[i];
    if (tid < 48) s_JT[tid] = JT[tid];
    s_WJ[tid] = WJ[tid];
    for (int i = tid; i < GC*152; i += 256) {
        int g = i / 152, k = i % 152, b = b0 + g;
        s_coef[g][k] = (b < Btot) ? coefG[(size_t)b*152 + k] : 0.f;
    }
    if (tid < GC*9) {
        int g = tid / 9, i2 = tid % 9, b = b0 + g;
        s_R0[g][i2] = (b < Btot) ? R0G[(size_t)b*9 + i2] : 0.f;
    }
    __syncthreads();

    // phase 1: J + kinematic chain; wave w handles g = pp*4 + w
    #pragma unroll
    for (int pp = 0; pp < 2; ++pp) {
        const int g = pp*4 + w;
        const int b = b0 + g;
        if (b < Btot) {
            if (t < 48) {
                float acc = s_JT[t];
                #pragma unroll
                for (int k = 0; k < 10; ++k) acc += s_coef[g][1+k] * s_SJ[k*48 + t];
                s_J[g][t] = acc;
            }
            if (t < 16) {
                float* Jg = s_J[g];
                float res[12];
                #pragma unroll
                for (int p = 0; p < 3; ++p) {
                    res[p*4+0] = s_R0[g][p*3+0];
                    res[p*4+1] = s_R0[g][p*3+1];
                    res[p*4+2] = s_R0[g][p*3+2];
                    res[p*4+3] = Jg[p];
                }
                if (t >= 1) {
                    int start = ((t-1)/3)*3 + 1;
                    int d = t - start;
                    for (int s = 0; s < 3; ++s) {
                        if (s <= d) {
                            int a  = start + s;
                            int pa = (s == 0) ? 0 : (a - 1);
                            const float* cr = &s_coef[g][11 + (a-1)*9];
                            float Ra[9];
                            #pragma unroll
                            for (int i2 = 0; i2 < 9; ++i2)
                                Ra[i2] = cr[i2] + ((i2 % 4 == 0) ? 1.f : 0.f);
                            float ax = Jg[a*3+0] - Jg[pa*3+0];
                            float ay = Jg[a*3+1] - Jg[pa*3+1];
                            float az = Jg[a*3+2] - Jg[pa*3+2];
                            float nr[12];
                            #pragma unroll
                            for (int p = 0; p < 3; ++p) {
                                float r0 = res[p*4+0], r1 = res[p*4+1], r2 = res[p*4+2];
                                #pragma unroll
                                for (int q = 0; q < 3; ++q)
                                    nr[p*4+q] = r0*Ra[q] + r1*Ra[3+q] + r2*Ra[6+q];
                                nr[p*4+3] = r0*ax + r1*ay + r2*az + res[p*4+3];
                            }
                            #pragma unroll
                            for (int q = 0; q < 12; ++q) res[q] = nr[q];
                        }
                    }
                }
                float jx = Jg[t*3+0], jy = Jg[t*3+1], jz = Jg[t*3+2];
                #pragma unroll
                for (int p = 0; p < 3; ++p) {
                    float r0 = res[p*4+0], r1 = res[p*4+1], r2 = res[p*4+2];
                    float ib = r0*jx + r1*jy + r2*jz;
                    s_A[g][t*12 + p*4+0] = r0;
                    s_A[g][t*12 + p*4+1] = r1;
                    s_A[g][t*12 + p*4+2] = r2;
                    s_A[g][t*12 + p*4+3] = res[p*4+3] - ib;
                }
            }
        }
    }
    __syncthreads();

    // phase 2: S[g][c][q] for c = tid, double-buffered 8-row groups
    float acc[GC][3];
    #pragma unroll
    for (int g = 0; g < GC; ++g) { acc[g][0]=0.f; acc[g][1]=0.f; acc[g][2]=0.f; }
    for (int k = 0; k < NKQ; k += 8) {
        float nxt0[8], nxt1[8], nxt2[8];
        if (k + 8 < NKQ) {
            #pragma unroll
            for (int kk = 0; kk < 8; ++kk) {
                const float* gq = Gq + ((size_t)(k+8+kk)*256 + tid)*3;
                nxt0[kk] = gq[0]; nxt1[kk] = gq[1]; nxt2[kk] = gq[2];
            }
        }
        #pragma unroll
        for (int g = 0; g < GC; ++g) {
            float4 cA = *(const float4*)&s_coef[g][k];
            float4 cB = *(const float4*)&s_coef[g][k+4];
            float cf[8] = {cA.x,cA.y,cA.z,cA.w, cB.x,cB.y,cB.z,cB.w};
            #pragma unroll
            for (int kk = 0; kk < 8; ++kk) {
                acc[g][0] += cf[kk]*cur0[kk];
                acc[g][1] += cf[kk]*cur1[kk];
                acc[g][2] += cf[kk]*cur2[kk];
            }
        }
        if (k + 8 < NKQ) {
            #pragma unroll
            for (int kk = 0; kk < 8; ++kk) {
                cur0[kk] = nxt0[kk]; cur1[kk] = nxt1[kk]; cur2[kk] = nxt2[kk];
            }
        }
    }

    // phase 3: joints via in-register 16-lane reduction
    {
        const int J = tid >> 4, j = tid & 15;
        #pragma unroll
        for (int g = 0; g < GC; ++g) {
            const float* Aj = &s_A[g][j*12];
            float wj = s_WJ[J*16 + j];
            float v0 = Aj[0]*acc[g][0] + Aj[1]*acc[g][1] + Aj[2]*acc[g][2]  + Aj[3]*wj;
            float v1 = Aj[4]*acc[g][0] + Aj[5]*acc[g][1] + Aj[6]*acc[g][2]  + Aj[7]*wj;
            float v2 = Aj[8]*acc[g][0] + Aj[9]*acc[g][1] + Aj[10]*acc[g][2] + Aj[11]*wj;
            #pragma unroll
            for (int off = 1; off < 16; off <<= 1) {
                v0 += __shfl_xor(v0, off, 64);
                v1 += __shfl_xor(v1, off, 64);
                v2 += __shfl_xor(v2, off, 64);
            }
            int b = b0 + g;
            if (j == 0 && b < Btot) {
                float* ob = out + (size_t)b*63 + J*3;
                ob[0] = v0; ob[1] = v1; ob[2] = v2;
            }
        }
    }

    // phase 4: finger vertices (2 k-slices of 73 + LDS merge)
    if (tid < GC*30) {
        int g = tid / 30, rem = tid % 30, sl = rem / 15, r = rem % 15;
        int k0 = sl*73, k1 = (k0+73 < NK) ? k0+73 : NK;
        float a = 0.f;
        for (int k = k0; k < k1; ++k) a += s_coef[g][k] * Dfing[k*15 + r];
        s_fred[g][r][sl] = a;
    }
    __syncthreads();
    if (tid < GC*15) {
        int g = tid / 15, r = tid % 15;
        s_vpf[g][r] = s_fred[g][r][0] + s_fred[g][r][1];
    }
    __syncthreads();
    if (tid < GC*15) {
        int g = tid / 15, r = tid % 15, f = r / 3, p = r % 3;
        int b = b0 + g;
        if (b < Btot) {
            const float* Ag = s_A[g];
            float vx = s_vpf[g][f*3+0], vy = s_vpf[g][f*3+1], vz = s_vpf[g][f*3+2];
            float val = 0.f;
            #pragma unroll
            for (int j = 0; j < 16; ++j) {
                float wj = Wfing[f*16 + j];
                val += wj * (Ag[j*12 + p*4 + 0]*vx +
                             Ag[j*12 + p*4 + 1]*vy +
                             Ag[j*12 + p*4 + 2]*vz +
                             Ag[j*12 + p*4 + 3]);
            }
            out[(size_t)b*63 + (16+f)*3 + p] = val;
        }
    }
}

extern "C" void kernel_launch(void* const* d_in, const int* in_sizes, int n_in,
                              void* d_out, int out_size, void* d_ws, size_t ws_size,
                              hipStream_t stream) {
    const float* beta       = (const float*)d_in[0];
    const float* theta      = (const float*)d_in[1];
    const float* v_template = (const float*)d_in[2];
    const float* shapedirs  = (const float*)d_in[3];
    const float* posedirs   = (const float*)d_in[4];
    const float* J_reg      = (const float*)d_in[5];
    const float* weights    = (const float*)d_in[6];
    const float* hands_mean = (const float*)d_in[7];
    const float* hands_comp = (const float*)d_in[8];
    float* out = (float*)d_out;

    const int B = in_sizes[0] / 10;
    const int nblk = (B + GC - 1) / GC;   // 512 for B=4096 -> 2 blocks/CU co-resident

    // workspace layout (floats)
    float* W = (float*)d_ws;
    float* SJ    = W;                    // 480
    float* JT    = W + 480;              // 48
    float* WJ    = W + 528;              // 256
    float* Dfing = W + 784;              // 2190
    float* Wfing = W + 2974;             // 80
    float* Gq    = W + 3072;             // 152*256*3 = 116736
    float* coefG = W + 119808;           // B*152
    float* R0G   = coefG + (size_t)B*152;// B*9

    void* args[] = {
        (void*)&v_template, (void*)&shapedirs, (void*)&posedirs,
        (void*)&J_reg, (void*)&weights,
        (void*)&beta, (void*)&theta, (void*)&hands_mean, (void*)&hands_comp,
        (void*)&SJ, (void*)&JT, (void*)&WJ, (void*)&Gq,
        (void*)&coefG, (void*)&R0G, (void*)&Dfing, (void*)&Wfing,
        (void*)&out, (void*)&B
    };
    hipLaunchCooperativeKernel((const void*)k_all, dim3(nblk), dim3(256),
                               args, 0, stream);
}

// Round 14
// 120.856 us; speedup vs baseline: 2.1847x; 2.1847x over previous
//
#include <hip/hip_runtime.h>

#define NV  778
#define NK  146    // coef: 1 (template) + 10 (beta) + 135 (pose_feature)
#define NKQ 152    // Gq rows padded to multiple of 8 (rows 146..151 zero)
#define GC  8      // batches per kC block (512 blocks = 2/CU)
#define VCH 98     // v-chunk per Gq fold block (8 chunks cover 778)
#define NCH 8      // chunk count

// Finger vertex ids
#define FV0 734
#define FV1 333
#define FV2 443
#define FV3 555
#define FV4 678

__device__ __forceinline__ const float* d_row(int k,
                                              const float* vt,
                                              const float* sd,
                                              const float* pd) {
    return (k == 0) ? vt : (k <= 10 ? sd + (size_t)(k-1)*(NV*3)
                                    : pd + (size_t)(k-11)*(NV*3));
}

// ---------------------------------------------------------------------------
// k_fold roles (blockIdx):
//   [0,1168)         Gq partials: Gqp[chunk][k][c][q] = sum_{v in chunk} ...
//                    PLAIN STORES (no atomics, no memset needed)
//   [1168,1300)      SJ[480]/JT[48]
//   [1300,1364)      WJ[256]
//   [1364,1364+npb)  pose PCA + Rodrigues -> coefG/R0G
//   1364+npb         Dfing/Wfing gathers
// ---------------------------------------------------------------------------
__launch_bounds__(256)
__global__ void k_fold(const float* __restrict__ vt,
                       const float* __restrict__ sd,
                       const float* __restrict__ pd,
                       const float* __restrict__ jreg,
                       const float* __restrict__ wts,
                       const float* __restrict__ beta,
                       const float* __restrict__ theta,
                       const float* __restrict__ hm,
                       const float* __restrict__ hc,
                       float* __restrict__ SJ, float* __restrict__ JT,
                       float* __restrict__ WJ, float* __restrict__ Gqp,
                       float* __restrict__ coefG, float* __restrict__ R0G,
                       float* __restrict__ Dfing, float* __restrict__ Wfing,
                       int Btot, int npb)
{
    const int o = blockIdx.x;
    const int tid = threadIdx.x;

    __shared__ float p_hc[2025];
    __shared__ float p_th[8][48];
    __shared__ float p_pose[8][45];
    __shared__ float l_j[VCH*16];
    __shared__ float l_w[VCH*16];
    __shared__ float l_d[VCH*3];

    if (o < 1168) {
        const int k = o >> 3, chunk = o & 7;
        const float* Drow = d_row(k, vt, sd, pd);
        const int v0 = chunk * VCH;
        const int v1 = (v0 + VCH < NV) ? (v0 + VCH) : NV;
        const int n = v1 - v0;
        for (int i = tid; i < n*16; i += 256) l_j[i] = jreg[v0*16 + i];
        for (int i = tid; i < n*16; i += 256) l_w[i] = wts[v0*16 + i];
        for (int i = tid; i < n*3;  i += 256) l_d[i] = Drow[v0*3 + i];
        __syncthreads();
        const int J = tid >> 4, j = tid & 15;
        float a0 = 0.f, a1 = 0.f, a2 = 0.f;
        #pragma unroll 7
        for (int v = 0; v < n; ++v) {
            float pv = l_j[v*16 + J] * l_w[v*16 + j];
            a0 += l_d[v*3+0] * pv;
            a1 += l_d[v*3+1] * pv;
            a2 += l_d[v*3+2] * pv;
        }
        float* gp = Gqp + (((size_t)chunk*NK + k)*256 + tid)*3;
        gp[0] = a0; gp[1] = a1; gp[2] = a2;
    } else if (o < 1300) {
        const int idx = (o - 1168)*4 + (tid >> 6);   // 0..527
        const int t = tid & 63;
        const float* src; int jc;
        if (idx < 480) { int k = idx / 48; jc = idx % 48; src = sd + (size_t)k*(NV*3); }
        else           { jc = idx - 480;              src = vt; }
        int j = jc / 3, c = jc % 3;
        float acc = 0.f;
        for (int v = t; v < NV; v += 64)
            acc += src[3*v + c] * jreg[v*16 + j];
        for (int off = 32; off; off >>= 1) acc += __shfl_down(acc, off, 64);
        if (t == 0) { if (idx < 480) SJ[idx] = acc; else JT[jc] = acc; }
    } else if (o < 1364) {
        const int cidx = (o - 1300)*4 + (tid >> 6);  // 0..255
        const int t = tid & 63;
        const int J = cidx >> 4, j = cidx & 15;
        float acc = 0.f;
        for (int v = t; v < NV; v += 64)
            acc += jreg[v*16 + J] * wts[v*16 + j];
        for (int off = 32; off; off >>= 1) acc += __shfl_down(acc, off, 64);
        if (t == 0) WJ[cidx] = acc;
    } else if (o < 1364 + npb) {
        const int b0 = (o - 1364) * 8;
        for (int i = tid; i < 2025; i += 256) p_hc[i] = hc[i];
        for (int i = tid; i < 8*48; i += 256) {
            int g = i / 48, t = i % 48, b = b0 + g;
            p_th[g][t] = (b < Btot) ? theta[(size_t)b*48 + t] : 0.f;
        }
        __syncthreads();
        for (int i = tid; i < 8*45; i += 256) {
            int g = i / 45, t = i % 45;
            float acc = hm[t];
            #pragma unroll 9
            for (int k = 0; k < 45; ++k) acc += p_th[g][3+k] * p_hc[k*45 + t];
            p_pose[g][t] = acc;
        }
        __syncthreads();
        if (tid < 128) {
            int g = tid >> 4, jt = tid & 15;
            int b = b0 + g;
            if (b < Btot) {
                float rx, ry, rz;
                if (jt == 0) { rx = p_th[g][0]; ry = p_th[g][1]; rz = p_th[g][2]; }
                else { rx = p_pose[g][3*(jt-1)+0]; ry = p_pose[g][3*(jt-1)+1]; rz = p_pose[g][3*(jt-1)+2]; }
                float ex = rx + 1e-8f, ey = ry + 1e-8f, ez = rz + 1e-8f;
                float angle = sqrtf(ex*ex + ey*ey + ez*ez);
                float inv = 1.f / angle;
                float x = rx*inv, y = ry*inv, z = rz*inv;
                float s  = sinf(angle);
                float c1 = 1.f - cosf(angle);
                float R[9];
                R[0] = 1.f + c1*(-(z*z + y*y));
                R[1] = -s*z + c1*(x*y);
                R[2] =  s*y + c1*(x*z);
                R[3] =  s*z + c1*(x*y);
                R[4] = 1.f + c1*(-(x*x + z*z));
                R[5] = -s*x + c1*(y*z);
                R[6] = -s*y + c1*(x*z);
                R[7] =  s*x + c1*(y*z);
                R[8] = 1.f + c1*(-(x*x + y*y));
                float* cg = coefG + (size_t)b*152;
                if (jt == 0) {
                    #pragma unroll
                    for (int i = 0; i < 9; ++i) R0G[(size_t)b*9 + i] = R[i];
                    cg[0] = 1.f;
                    #pragma unroll
                    for (int k = 0; k < 10; ++k) cg[1+k] = beta[(size_t)b*10 + k];
                    #pragma unroll
                    for (int k = 146; k < 152; ++k) cg[k] = 0.f;
                } else {
                    #pragma unroll
                    for (int i = 0; i < 9; ++i)
                        cg[11 + (jt-1)*9 + i] = R[i] - ((i % 4 == 0) ? 1.f : 0.f);
                }
            }
        }
    } else {
        const int fv[5] = {FV0, FV1, FV2, FV3, FV4};
        for (int e = tid; e < NK*15; e += 256) {
            int k = e / 15, r = e % 15, f = r / 3, q = r % 3;
            Dfing[e] = d_row(k, vt, sd, pd)[3*fv[f] + q];
        }
        if (tid < 80) {
            int f = tid >> 4, j = tid & 15;
            Wfing[tid] = wts[fv[f]*16 + j];
        }
    }
}

// ---------------------------------------------------------------------------
// k_red: Gq[k][c][q] = sum_ch Gqp[ch][k][c][q]; zeros for padded rows.
// ---------------------------------------------------------------------------
__launch_bounds__(256)
__global__ void k_red(const float* __restrict__ Gqp, float* __restrict__ Gq)
{
    const int k = blockIdx.x;      // 0..NKQ-1
    const int c = threadIdx.x;     // 0..255
    float a0 = 0.f, a1 = 0.f, a2 = 0.f;
    if (k < NK) {
        #pragma unroll
        for (int ch = 0; ch < NCH; ++ch) {
            const float* gp = Gqp + (((size_t)ch*NK + k)*256 + c)*3;
            a0 += gp[0]; a1 += gp[1]; a2 += gp[2];
        }
    }
    float* g = Gq + ((size_t)k*256 + c)*3;
    g[0] = a0; g[1] = a1; g[2] = a2;
}

// ---------------------------------------------------------------------------
// kC: unchanged from R12 (GC=8, 512 blocks, double-buffered phase 2).
// ---------------------------------------------------------------------------
__launch_bounds__(256)
__global__ void kC(const float* __restrict__ SJ,
                   const float* __restrict__ JT,
                   const float* __restrict__ WJ,
                   const float* __restrict__ Gq,
                   const float* __restrict__ coefG,
                   const float* __restrict__ R0G,
                   const float* __restrict__ Dfing,
                   const float* __restrict__ Wfing,
                   float* __restrict__ out,
                   int Btot)
{
    const int tid = threadIdx.x;
    const int w = tid >> 6, t = tid & 63;
    const int b0 = blockIdx.x * GC;

    __shared__ float s_SJ[480];
    __shared__ float s_JT[48];
    __shared__ float s_WJ[256];
    __shared__ __align__(16) float s_coef[GC][152];
    __shared__ float s_R0[GC][9];
    __shared__ float s_A[GC][192];
    __shared__ float s_J[GC][48];
    __shared__ float s_vpf[GC][16];
    __shared__ float s_fred[GC][15][2];

    float cur0[8], cur1[8], cur2[8];
    #pragma unroll
    for (int kk = 0; kk < 8; ++kk) {
        const float* gq = Gq + ((size_t)kk*256 + tid)*3;
        cur0[kk] = gq[0]; cur1[kk] = gq[1]; cur2[kk] = gq[2];
    }

    for (int i = tid; i < 480; i += 256) s_SJ[i] = SJ[i];
    if (tid < 48) s_JT[tid] = JT[tid];
    s_WJ[tid] = WJ[tid];
    for (int i = tid; i < GC*152; i += 256) {
        int g = i / 152, k = i % 152, b = b0 + g;
        s_coef[g][k] = (b < Btot) ? coefG[(size_t)b*152 + k] : 0.f;
    }
    if (tid < GC*9) {
        int g = tid / 9, i = tid % 9, b = b0 + g;
        s_R0[g][i] = (b < Btot) ? R0G[(size_t)b*9 + i] : 0.f;
    }
    __syncthreads();

    #pragma unroll
    for (int pp = 0; pp < 2; ++pp) {
        const int g = pp*4 + w;
        const int b = b0 + g;
        if (b < Btot) {
            if (t < 48) {
                float acc = s_JT[t];
                #pragma unroll
                for (int k = 0; k < 10; ++k) acc += s_coef[g][1+k] * s_SJ[k*48 + t];
                s_J[g][t] = acc;
            }
            if (t < 16) {
                float* Jg = s_J[g];
                float res[12];
                #pragma unroll
                for (int p = 0; p < 3; ++p) {
                    res[p*4+0] = s_R0[g][p*3+0];
                    res[p*4+1] = s_R0[g][p*3+1];
                    res[p*4+2] = s_R0[g][p*3+2];
                    res[p*4+3] = Jg[p];
                }
                if (t >= 1) {
                    int start = ((t-1)/3)*3 + 1;
                    int d = t - start;
                    for (int s = 0; s < 3; ++s) {
                        if (s <= d) {
                            int a  = start + s;
                            int pa = (s == 0) ? 0 : (a - 1);
                            const float* cr = &s_coef[g][11 + (a-1)*9];
                            float Ra[9];
                            #pragma unroll
                            for (int i = 0; i < 9; ++i)
                                Ra[i] = cr[i] + ((i % 4 == 0) ? 1.f : 0.f);
                            float ax = Jg[a*3+0] - Jg[pa*3+0];
                            float ay = Jg[a*3+1] - Jg[pa*3+1];
                            float az = Jg[a*3+2] - Jg[pa*3+2];
                            float nr[12];
                            #pragma unroll
                            for (int p = 0; p < 3; ++p) {
                                float r0 = res[p*4+0], r1 = res[p*4+1], r2 = res[p*4+2];
                                #pragma unroll
                                for (int q = 0; q < 3; ++q)
                                    nr[p*4+q] = r0*Ra[q] + r1*Ra[3+q] + r2*Ra[6+q];
                                nr[p*4+3] = r0*ax + r1*ay + r2*az + res[p*4+3];
                            }
                            #pragma unroll
                            for (int q = 0; q < 12; ++q) res[q] = nr[q];
                        }
                    }
                }
                float jx = Jg[t*3+0], jy = Jg[t*3+1], jz = Jg[t*3+2];
                #pragma unroll
                for (int p = 0; p < 3; ++p) {
                    float r0 = res[p*4+0], r1 = res[p*4+1], r2 = res[p*4+2];
                    float ib = r0*jx + r1*jy + r2*jz;
                    s_A[g][t*12 + p*4+0] = r0;
                    s_A[g][t*12 + p*4+1] = r1;
                    s_A[g][t*12 + p*4+2] = r2;
                    s_A[g][t*12 + p*4+3] = res[p*4+3] - ib;
                }
            }
        }
    }
    __syncthreads();

    float acc[GC][3];
    #pragma unroll
    for (int g = 0; g < GC; ++g) { acc[g][0]=0.f; acc[g][1]=0.f; acc[g][2]=0.f; }
    for (int k = 0; k < NKQ; k += 8) {
        float nxt0[8], nxt1[8], nxt2[8];
        if (k + 8 < NKQ) {
            #pragma unroll
            for (int kk = 0; kk < 8; ++kk) {
                const float* gq = Gq + ((size_t)(k+8+kk)*256 + tid)*3;
                nxt0[kk] = gq[0]; nxt1[kk] = gq[1]; nxt2[kk] = gq[2];
            }
        }
        #pragma unroll
        for (int g = 0; g < GC; ++g) {
            float4 cA = *(const float4*)&s_coef[g][k];
            float4 cB = *(const float4*)&s_coef[g][k+4];
            float cf[8] = {cA.x,cA.y,cA.z,cA.w, cB.x,cB.y,cB.z,cB.w};
            #pragma unroll
            for (int kk = 0; kk < 8; ++kk) {
                acc[g][0] += cf[kk]*cur0[kk];
                acc[g][1] += cf[kk]*cur1[kk];
                acc[g][2] += cf[kk]*cur2[kk];
            }
        }
        if (k + 8 < NKQ) {
            #pragma unroll
            for (int kk = 0; kk < 8; ++kk) {
                cur0[kk] = nxt0[kk]; cur1[kk] = nxt1[kk]; cur2[kk] = nxt2[kk];
            }
        }
    }

    {
        const int J = tid >> 4, j = tid & 15;
        #pragma unroll
        for (int g = 0; g < GC; ++g) {
            const float* Aj = &s_A[g][j*12];
            float wj = s_WJ[J*16 + j];
            float v0 = Aj[0]*acc[g][0] + Aj[1]*acc[g][1] + Aj[2]*acc[g][2]  + Aj[3]*wj;
            float v1 = Aj[4]*acc[g][0] + Aj[5]*acc[g][1] + Aj[6]*acc[g][2]  + Aj[7]*wj;
            float v2 = Aj[8]*acc[g][0] + Aj[9]*acc[g][1] + Aj[10]*acc[g][2] + Aj[11]*wj;
            #pragma unroll
            for (int off = 1; off < 16; off <<= 1) {
                v0 += __shfl_xor(v0, off, 64);
                v1 += __shfl_xor(v1, off, 64);
                v2 += __shfl_xor(v2, off, 64);
            }
            int b = b0 + g;
            if (j == 0 && b < Btot) {
                float* ob = out + (size_t)b*63 + J*3;
                ob[0] = v0; ob[1] = v1; ob[2] = v2;
            }
        }
    }

    if (tid < GC*30) {
        int g = tid / 30, rem = tid % 30, sl = rem / 15, r = rem % 15;
        int k0 = sl*73, k1 = (k0+73 < NK) ? k0+73 : NK;
        float a = 0.f;
        for (int k = k0; k < k1; ++k) a += s_coef[g][k] * Dfing[k*15 + r];
        s_fred[g][r][sl] = a;
    }
    __syncthreads();
    if (tid < GC*15) {
        int g = tid / 15, r = tid % 15;
        s_vpf[g][r] = s_fred[g][r][0] + s_fred[g][r][1];
    }
    __syncthreads();
    if (tid < GC*15) {
        int g = tid / 15, r = tid % 15, f = r / 3, p = r % 3;
        int b = b0 + g;
        if (b < Btot) {
            const float* Ag = s_A[g];
            float vx = s_vpf[g][f*3+0], vy = s_vpf[g][f*3+1], vz = s_vpf[g][f*3+2];
            float val = 0.f;
            #pragma unroll
            for (int j = 0; j < 16; ++j) {
                float wj = Wfing[f*16 + j];
                val += wj * (Ag[j*12 + p*4 + 0]*vx +
                             Ag[j*12 + p*4 + 1]*vy +
                             Ag[j*12 + p*4 + 2]*vz +
                             Ag[j*12 + p*4 + 3]);
            }
            out[(size_t)b*63 + (16+f)*3 + p] = val;
        }
    }
}

extern "C" void kernel_launch(void* const* d_in, const int* in_sizes, int n_in,
                              void* d_out, int out_size, void* d_ws, size_t ws_size,
                              hipStream_t stream) {
    const float* beta       = (const float*)d_in[0];
    const float* theta      = (const float*)d_in[1];
    const float* v_template = (const float*)d_in[2];
    const float* shapedirs  = (const float*)d_in[3];
    const float* posedirs   = (const float*)d_in[4];
    const float* J_reg      = (const float*)d_in[5];
    const float* weights    = (const float*)d_in[6];
    const float* hands_mean = (const float*)d_in[7];
    const float* hands_comp = (const float*)d_in[8];
    float* out = (float*)d_out;

    const int B = in_sizes[0] / 10;
    const int npb = (B + 7) / 8;

    // workspace layout (floats)
    float* W = (float*)d_ws;
    float* SJ    = W;                          // 480
    float* JT    = W + 480;                    // 48
    float* WJ    = W + 528;                    // 256
    float* Dfing = W + 784;                    // 2190
    float* Wfing = W + 2974;                   // 80
    float* Gq    = W + 3072;                   // 152*256*3 = 116736
    float* Gqp   = W + 119808;                 // 8*146*768 = 897024
    float* coefG = W + 1016832;                // B*152
    float* R0G   = coefG + (size_t)B*152;      // B*9

    k_fold<<<1365 + npb, 256, 0, stream>>>(v_template, shapedirs, posedirs, J_reg,
                                           weights, beta, theta, hands_mean, hands_comp,
                                           SJ, JT, WJ, Gqp, coefG, R0G, Dfing, Wfing,
                                           B, npb);
    k_red<<<NKQ, 256, 0, stream>>>(Gqp, Gq);
    kC<<<(B + GC - 1)/GC, 256, 0, stream>>>(SJ, JT, WJ, Gq, coefG, R0G,
                                            Dfing, Wfing, out, B);
}